// Round 2
// baseline (675.689 us; speedup 1.0000x reference)
//
#include <hip/hip_runtime.h>
#include <hip/hip_bf16.h>

// VQ EuclideanCodebook fused kernel, f32 VALU baseline (round 2).
// dist = (x2 - 2*x.e) + e2 computed in the reference's op order to keep
// argmin tie behavior aligned with the np/jax f32 reference.

#define NROWS 262144
#define KCODES 1024
#define DDIM 64

#define BM 256        // rows per block
#define BK 256        // codes per chunk
#define TM 16         // rows per thread
#define TK 8          // codes per thread (per chunk)
#define NTHR 512
#define LDX 260       // BM + 4 pad (keeps rows 16B-aligned, breaks pow2 bank stride)
#define LDE 260
#define NCHUNK (KCODES / BK)

__global__ __launch_bounds__(NTHR, 2) void vq_main(
    const float* __restrict__ x, const float* __restrict__ embed,
    float* __restrict__ out_q, float* __restrict__ out_ind,
    float* __restrict__ bins, float* __restrict__ embed_sum)
{
    __shared__ float xs[DDIM][LDX];   // x tile, transposed [d][row]
    __shared__ float es[DDIM][LDE];   // embed chunk, transposed [d][code]
    __shared__ float x2s[BM];
    __shared__ float e2s[BK];
    __shared__ int   inds[BM];

    const int t    = threadIdx.x;
    const int row0 = blockIdx.x * BM;
    const int tc   = t & 31;          // 32 code-groups
    const int tr   = t >> 5;          // 16 row-groups
    const int r0   = tr * TM;
    const int c0   = tc * 4;          // first 4-code quad; second quad at +128

    // ---- stage x tile transposed (coalesced global float4 reads) ----
    #pragma unroll
    for (int i = 0; i < 8; ++i) {
        int f = t + i * NTHR;                 // 0..4095 over BM*16 float4s
        int row = f >> 4, dq = f & 15;
        const float4 v = *reinterpret_cast<const float4*>(
            x + (size_t)(row0 + row) * DDIM + dq * 4);
        xs[dq*4+0][row] = v.x; xs[dq*4+1][row] = v.y;
        xs[dq*4+2][row] = v.z; xs[dq*4+3][row] = v.w;
    }
    __syncthreads();

    // x2 per row (ascending-d f32, mimics reference order closely)
    if (t < BM) {
        float s = 0.f;
        #pragma unroll
        for (int d = 0; d < DDIM; ++d) { float v = xs[d][t]; s = fmaf(v, v, s); }
        x2s[t] = s;
    }

    float bestv[TM];
    int   besti[TM];
    #pragma unroll
    for (int i = 0; i < TM; ++i) { bestv[i] = 3.4e38f; besti[i] = 0; }

    for (int ch = 0; ch < NCHUNK; ++ch) {
        __syncthreads();   // protect es/e2s from previous chunk's readers
        #pragma unroll
        for (int i = 0; i < 8; ++i) {
            int f = t + i * NTHR;                 // 0..4095 over BK*16 float4s
            int code = f >> 4, dq = f & 15;
            const float4 v = *reinterpret_cast<const float4*>(
                embed + (size_t)(ch * BK + code) * DDIM + dq * 4);
            es[dq*4+0][code] = v.x; es[dq*4+1][code] = v.y;
            es[dq*4+2][code] = v.z; es[dq*4+3][code] = v.w;
        }
        __syncthreads();
        if (t < BK) {
            float s = 0.f;
            #pragma unroll
            for (int d = 0; d < DDIM; ++d) { float v = es[d][t]; s = fmaf(v, v, s); }
            e2s[t] = s;
        }
        __syncthreads();

        float acc[TM][TK];
        #pragma unroll
        for (int i = 0; i < TM; ++i)
            #pragma unroll
            for (int j = 0; j < TK; ++j) acc[i][j] = 0.f;

        #pragma unroll 2
        for (int d = 0; d < DDIM; ++d) {
            float xf[TM], ef[TK];
            #pragma unroll
            for (int j = 0; j < 4; ++j) {
                const float4 v = *reinterpret_cast<const float4*>(&xs[d][r0 + 4*j]);
                xf[4*j+0] = v.x; xf[4*j+1] = v.y; xf[4*j+2] = v.z; xf[4*j+3] = v.w;
            }
            {   // two b128 quads: codes [4tc..4tc+3] and [128+4tc..128+4tc+3]
                const float4 v0 = *reinterpret_cast<const float4*>(&es[d][c0]);
                ef[0] = v0.x; ef[1] = v0.y; ef[2] = v0.z; ef[3] = v0.w;
                const float4 v1 = *reinterpret_cast<const float4*>(&es[d][128 + c0]);
                ef[4] = v1.x; ef[5] = v1.y; ef[6] = v1.z; ef[7] = v1.w;
            }
            #pragma unroll
            for (int i = 0; i < TM; ++i)
                #pragma unroll
                for (int j = 0; j < TK; ++j)
                    acc[i][j] = fmaf(xf[i], ef[j], acc[i][j]);
        }

        // running argmin; j scans this thread's codes in ascending global index,
        // strict < keeps the FIRST (lowest) index on ties.
        #pragma unroll
        for (int i = 0; i < TM; ++i) {
            const float x2 = x2s[r0 + i];
            #pragma unroll
            for (int j = 0; j < TK; ++j) {
                const int cc = (j < 4) ? (c0 + j) : (128 + c0 + (j - 4));
                const float dist = (x2 - 2.0f * acc[i][j]) + e2s[cc];
                if (dist < bestv[i]) { bestv[i] = dist; besti[i] = ch * BK + cc; }
            }
        }
    }

    // ---- cross-thread argmin merge (reuse es storage: 32*BM floats + 32*BM ints) ----
    __syncthreads();
    float* rv = &es[0][0];
    int*   ri = reinterpret_cast<int*>(rv + 32 * BM);
    #pragma unroll
    for (int i = 0; i < TM; ++i) {
        rv[tc * BM + r0 + i] = bestv[i];
        ri[tc * BM + r0 + i] = besti[i];
    }
    __syncthreads();
    if (t < BM) {
        float bv = rv[t]; int bi = ri[t];
        for (int q = 1; q < 32; ++q) {
            float v = rv[q * BM + t]; int ii = ri[q * BM + t];
            if (v < bv || (v == bv && ii < bi)) { bv = v; bi = ii; }
        }
        inds[t] = bi;
        out_ind[row0 + t] = (float)bi;          // index as float (d_out is f32)
        unsafeAtomicAdd(bins + bi, 1.0f);       // exact: integer counts in f32
    }
    __syncthreads();

    // ---- quantize gather + embed_sum scatter ----
    #pragma unroll
    for (int i = 0; i < 8; ++i) {
        int f = t + i * NTHR;                   // 0..4095 over BM*16 float4s
        int r = f >> 4, dq = f & 15;
        int code = inds[r];
        const float4 ev = *reinterpret_cast<const float4*>(
            embed + (size_t)code * DDIM + dq * 4);
        *reinterpret_cast<float4*>(out_q + (size_t)(row0 + r) * DDIM + dq * 4) = ev;
        unsafeAtomicAdd(embed_sum + code * DDIM + dq*4 + 0, xs[dq*4+0][r]);
        unsafeAtomicAdd(embed_sum + code * DDIM + dq*4 + 1, xs[dq*4+1][r]);
        unsafeAtomicAdd(embed_sum + code * DDIM + dq*4 + 2, xs[dq*4+2][r]);
        unsafeAtomicAdd(embed_sum + code * DDIM + dq*4 + 3, xs[dq*4+3][r]);
    }
}

__global__ void vq_zero(float* __restrict__ p, int n)
{
    int i = blockIdx.x * blockDim.x + threadIdx.x;
    if (i < n) p[i] = 0.f;
}

// Reads bins from out_cs (accumulated in-place) and embed_sum from out_eavg,
// rewrites both with the EMA results and writes out_enorm.
__global__ __launch_bounds__(1024) void vq_finalize(
    const float* __restrict__ cluster_size, const float* __restrict__ embed_avg,
    float* __restrict__ out_cs, float* __restrict__ out_eavg,
    float* __restrict__ out_enorm)
{
    __shared__ float red[KCODES];
    __shared__ float css[KCODES];
    const int t = threadIdx.x;

    const float csn = cluster_size[t] * 0.1f + out_cs[t] * 0.9f;
    red[t] = csn;
    __syncthreads();
    for (int s = 512; s > 0; s >>= 1) {
        if (t < s) red[t] += red[t + s];
        __syncthreads();
    }
    const float n = red[0];
    out_cs[t] = csn;
    css[t] = (csn + 1e-5f) / (n + (float)(KCODES * 1e-5)) * n;
    __syncthreads();

    #pragma unroll
    for (int i = 0; i < 16; ++i) {
        int f4 = t + i * 1024;                  // over KCODES*DDIM/4 = 16384 float4s
        int k  = f4 >> 4;
        const float4 ea = reinterpret_cast<const float4*>(embed_avg)[f4];
        const float4 su = reinterpret_cast<const float4*>(out_eavg)[f4];
        const float  c  = css[k];
        float4 ean, en;
        ean.x = ea.x * 0.1f + su.x * 0.9f; en.x = ean.x / c;
        ean.y = ea.y * 0.1f + su.y * 0.9f; en.y = ean.y / c;
        ean.z = ea.z * 0.1f + su.z * 0.9f; en.z = ean.z / c;
        ean.w = ea.w * 0.1f + su.w * 0.9f; en.w = ean.w / c;
        reinterpret_cast<float4*>(out_eavg)[f4]  = ean;
        reinterpret_cast<float4*>(out_enorm)[f4] = en;
    }
}

extern "C" void kernel_launch(void* const* d_in, const int* in_sizes, int n_in,
                              void* d_out, int out_size, void* d_ws, size_t ws_size,
                              hipStream_t stream)
{
    const float* x            = (const float*)d_in[0];
    const float* embed        = (const float*)d_in[1];
    const float* cluster_size = (const float*)d_in[2];
    const float* embed_avg    = (const float*)d_in[3];

    float* out      = (float*)d_out;
    float* out_q    = out;                                   // N*D
    float* out_ind  = out_q + (size_t)NROWS * DDIM;          // N
    float* out_cs   = out_ind + NROWS;                       // K      (bins accumulator)
    float* out_eavg = out_cs + KCODES;                       // K*D    (embed_sum accumulator)
    float* out_en   = out_eavg + (size_t)KCODES * DDIM;      // K*D

    // zero the two accumulator regions (out_cs .. out_eavg end)
    const int nz = KCODES + KCODES * DDIM;                   // 66560
    vq_zero<<<(nz + 255) / 256, 256, 0, stream>>>(out_cs, nz);
    vq_main<<<NROWS / BM, NTHR, 0, stream>>>(x, embed, out_q, out_ind, out_cs, out_eavg);
    vq_finalize<<<1, 1024, 0, stream>>>(cluster_size, embed_avg, out_cs, out_eavg, out_en);
}